// Round 1
// baseline (385.190 us; speedup 1.0000x reference)
//
#include <hip/hip_runtime.h>
#include <hip/hip_bf16.h>

#define NFRAME 2
#define NATOMS 4096
#define NNEI 138
#define SEL0 46
#define N1 24
#define N2 48
#define N3 96
#define ROWLEN 97
// G region: NNEI*ROWLEN = 13386 floats, pad to multiple of 4 for float4-aligned d
#define DOFF 13388
#define GROFF (DOFF + NNEI * 4)          // 13940
#define SMEM_FLOATS (GROFF + 4 * N3)     // 14324 floats = 57296 bytes

__device__ __forceinline__ float fexp2(float x) {
#if __has_builtin(__builtin_amdgcn_exp2f)
    return __builtin_amdgcn_exp2f(x);
#else
    return exp2f(x);
#endif
}

__device__ __forceinline__ float frcp(float x) {
#if __has_builtin(__builtin_amdgcn_rcpf)
    return __builtin_amdgcn_rcpf(x);
#else
    return 1.0f / x;
#endif
}

// tanh(x) = 1 - 2/(exp(2x)+1); saturates to +/-1 for |x| large (inf-safe)
__device__ __forceinline__ float fast_tanh(float x) {
    float e = fexp2(x * 2.8853900817779268f);  // exp(2x) = 2^(2x*log2(e))
    return 1.0f - 2.0f * frcp(e + 1.0f);
}

__global__ __launch_bounds__(192, 2) void descrpt_sea_kernel(
    const float* __restrict__ coord,
    const float* __restrict__ davg,
    const float* __restrict__ dstd,
    const float* __restrict__ W1, const float* __restrict__ b1,
    const float* __restrict__ W2, const float* __restrict__ b2,
    const float* __restrict__ W3, const float* __restrict__ b3,
    const int* __restrict__ atype, const int* __restrict__ nlist,
    float* __restrict__ out)
{
    __shared__ float smem[SMEM_FLOATS];
    const int bid  = blockIdx.x;          // f*NATOMS + n
    const int f    = bid >> 12;           // NATOMS = 4096
    const int tid  = threadIdx.x;
    const int wid  = tid >> 6;
    const int lane = tid & 63;

    // lane -> neighbor mapping; each wave is segment-uniform:
    // wave0: i=0..45 (type 0), wave1: i=46..109 (type 1), wave2: i=110..137 (type 1)
    int i;
    bool active;
    if (wid == 0)      { i = lane;             active = (lane < SEL0); }
    else if (wid == 1) { i = SEL0 + lane;      active = true; }
    else               { i = SEL0 + 64 + lane; active = (i < NNEI); }
    const int tseg = __builtin_amdgcn_readfirstlane((wid == 0) ? 0 : 1);
    const int im = active ? i : 0;

    const float cx = coord[bid * 3 + 0];
    const float cy = coord[bid * 3 + 1];
    const float cz = coord[bid * 3 + 2];
    const int at = atype[bid];

    // ---- phase 1: environment matrix d (per-neighbor) ----
    float x = 0.0f;
    if (active) {
        const int nl = nlist[bid * NNEI + i];
        const float* nc = coord + ((size_t)f * NATOMS + (size_t)nl) * 3;
        float dx = nc[0] - cx, dy = nc[1] - cy, dz = nc[2] - cz;
        float rsq = dx * dx + dy * dy + dz * dz;
        float r = sqrtf(fmaxf(rsq, 1e-12f));
        float uu = (r - 0.5f) * (1.0f / 5.5f);
        float vv = uu * uu * uu * (uu * (-6.0f * uu + 15.0f) - 10.0f) + 1.0f;
        float sw = (r < 0.5f) ? 1.0f : ((r < 6.0f) ? vv : 0.0f);
        float rinv = frcp(r);
        float s = sw * rinv;
        float sor = s * rinv;
        const float* avg  = davg + ((size_t)at * NNEI + i) * 4;
        const float* stdp = dstd + ((size_t)at * NNEI + i) * 4;
        float d0 = (s        - avg[0]) / stdp[0];
        float d1 = (sor * dx - avg[1]) / stdp[1];
        float d2 = (sor * dy - avg[2]) / stdp[2];
        float d3 = (sor * dz - avg[3]) / stdp[3];
        x = d0;
        float4 dv; dv.x = d0; dv.y = d1; dv.z = d2; dv.w = d3;
        *reinterpret_cast<float4*>(&smem[DOFF + i * 4]) = dv;
    }

    // per-segment weights: wave-uniform base -> scalar loads
    const float* W1p = W1 + tseg * N1;
    const float* b1p = b1 + tseg * N1;
    const float* W2p = W2 + tseg * (N1 * N2);
    const float* b2p = b2 + tseg * N2;
    const float* W3p = W3 + tseg * (N2 * N3);
    const float* b3p = b3 + tseg * N3;

    // private LDS row for this lane: [0..47] x2 (later G[0..95]), [48..71] h1
    float* row = &smem[im * ROWLEN];

    if (active) {
        // ---- stage B: h1 = tanh(x*W1 + b1) ----
        #pragma unroll
        for (int j = 0; j < N1; ++j)
            row[N2 + j] = fast_tanh(fmaf(x, W1p[j], b1p[j]));

        // ---- stage C: x2 = concat(h1,h1) + tanh(h1@W2 + b2) ----
        float acc2[N2];
        #pragma unroll
        for (int j = 0; j < N2; ++j) acc2[j] = b2p[j];
        #pragma unroll 4
        for (int k = 0; k < N1; ++k) {
            float hk = row[N2 + k];
            #pragma unroll
            for (int j = 0; j < N2; ++j)
                acc2[j] = fmaf(hk, W2p[k * N2 + j], acc2[j]);
        }
        #pragma unroll
        for (int j = 0; j < N2; ++j) {
            const int jm = (j < N1) ? j : (j - N1);
            row[j] = row[N2 + jm] + fast_tanh(acc2[j]);
        }

        // ---- stage D: G = concat(x2,x2) + tanh(x2@W3 + b3) ----
        float acc3[N3];
        #pragma unroll
        for (int j = 0; j < N3; ++j) acc3[j] = b3p[j];
        #pragma unroll 2
        for (int k = 0; k < N2; ++k) {
            float xk = row[k];
            #pragma unroll
            for (int j = 0; j < N3; ++j)
                acc3[j] = fmaf(xk, W3p[k * N3 + j], acc3[j]);
        }
        // write G over the row; pair (j, j+48) shares x2[j], read-before-write safe
        #pragma unroll
        for (int j = 0; j < N2; ++j) {
            float xv = row[j];
            row[j]      = xv + fast_tanh(acc3[j]);
            row[j + N2] = xv + fast_tanh(acc3[j + N2]);
        }
    }

    __syncthreads();

    // ---- gr[a][m] = sum_i d[i][a]*G[i][m] / NNEI ----
    {
        const int m  = tid % 96;
        const int a1 = tid / 96;   // 0 or 1
        const int a2 = a1 + 2;
        float s1 = 0.0f, s2 = 0.0f;
        #pragma unroll 2
        for (int ii = 0; ii < NNEI; ++ii) {
            float g  = smem[ii * ROWLEN + m];
            float da = smem[DOFF + ii * 4 + a1];
            float db = smem[DOFF + ii * 4 + a2];
            s1 = fmaf(da, g, s1);
            s2 = fmaf(db, g, s2);
        }
        const float inv = 1.0f / (float)NNEI;
        smem[GROFF + a1 * 96 + m] = s1 * inv;
        smem[GROFF + a2 * 96 + m] = s2 * inv;
    }

    __syncthreads();

    // ---- D[m][k] = sum_a gr[a][m]*gr[a][k], k<8; coalesced store ----
    {
        const float* gr = &smem[GROFF];
        const size_t base = (size_t)bid * 768;
        #pragma unroll
        for (int rep = 0; rep < 4; ++rep) {
            const int o  = tid + rep * 192;
            const int mm = o >> 3;
            const int kk = o & 7;
            float acc = 0.0f;
            #pragma unroll
            for (int a = 0; a < 4; ++a)
                acc = fmaf(gr[a * 96 + mm], gr[a * 96 + kk], acc);
            out[base + o] = acc;
        }
    }
}

extern "C" void kernel_launch(void* const* d_in, const int* in_sizes, int n_in,
                              void* d_out, int out_size, void* d_ws, size_t ws_size,
                              hipStream_t stream) {
    const float* coord = (const float*)d_in[0];
    const float* davg  = (const float*)d_in[1];
    const float* dstd  = (const float*)d_in[2];
    const float* W1    = (const float*)d_in[3];
    const float* b1    = (const float*)d_in[4];
    const float* W2    = (const float*)d_in[5];
    const float* b2    = (const float*)d_in[6];
    const float* W3    = (const float*)d_in[7];
    const float* b3    = (const float*)d_in[8];
    const int*   atype = (const int*)d_in[9];
    const int*   nlist = (const int*)d_in[10];
    float* out = (float*)d_out;

    descrpt_sea_kernel<<<dim3(NFRAME * NATOMS), dim3(192), 0, stream>>>(
        coord, davg, dstd, W1, b1, W2, b2, W3, b3, atype, nlist, out);
}